// Round 16
// baseline (170.222 us; speedup 1.0000x reference)
//
#include <hip/hip_runtime.h>

typedef unsigned short u16;
typedef __attribute__((ext_vector_type(8))) short short8;   // 8 bf16 (guide-verified MFMA frag type)
typedef __attribute__((ext_vector_type(4))) float f32x4;

// Workspace layout (u16 element offsets).
#define XCB_OFF  0          // xc  channels-last bf16 [2][16^4][64] = 8,388,608
#define Y1B_OFF  8388608    // Y1  channels-last bf16 [2][16^4][32] = 4,194,304
#define W1P_OFF  12582912   // w1 prepacked [tap81][chunk2][half2][lane64][8] = 165,888
#define W2P_OFF  12748800   // w2 prepacked [tap81][half2][lane64][8]         =  82,944
#define W3P_OFF  12831744   // w3 prepacked [chunk2][half2][lane64][8]        =   2,048
#define UPWP_OFF 12833792   // up_w prepacked [tap16][chunk2][half2][lane64][8] = 32,768
#define ZPAD_OFF 12866560   // 64 u16 of zeros — OOB redirect target (gload + direct reads)

__device__ __forceinline__ u16 f2bf(float v) {   // RNE fp32 -> bf16 bits
    unsigned u = __builtin_bit_cast(unsigned, v);
    u += 0x7FFFu + ((u >> 16) & 1u);
    return (u16)(u >> 16);
}

__device__ __forceinline__ f32x4 MFMA(short8 a, short8 b, f32x4 c) {
    return __builtin_amdgcn_mfma_f32_16x16x32_bf16(a, b, c, 0, 0, 0);
}

// async global->LDS, 16B per lane. LDS dest must be linear (wave base + lane*16);
// global source is per-lane (pre-swizzled / OOB-redirected).
typedef const __attribute__((address_space(1))) u16 gas_u16;
typedef __attribute__((address_space(3))) u16 las_u16;
__device__ __forceinline__ void gload16(const u16* g, u16* l) {
    __builtin_amdgcn_global_load_lds((gas_u16*)g, (las_u16*)l, 16, 0, 0);
}

// ---------------------------------------------------------------------------
// setup (r14 form): grid 512; prepack folded into xc_copy blocks, 3/thread.
// ---------------------------------------------------------------------------
__global__ __launch_bounds__(256) void setup(const float* __restrict__ w1,
                                             const float* __restrict__ w2,
                                             const float* __restrict__ w3,
                                             const float* __restrict__ upw,
                                             const float* __restrict__ x2,
                                             u16* __restrict__ ws) {
    __shared__ u16 lds[256 * 40];
    int bid = blockIdx.x;
    int tid = threadIdx.x;
    if (bid == 0 && tid < 64) ws[ZPAD_OFF + tid] = 0;   // zero redirect target

    // ---- prepack (3 elems/thread, folded in) ----
    #pragma unroll
    for (int k = 0; k < 3; ++k) {
        int idx = k * 131072 + bid * 256 + tid;
        if (idx < 165888) {
            int j = idx & 7, lane = (idx >> 3) & 63, rest = idx >> 9;
            int half = rest & 1, chunk = (rest >> 1) & 1, tap = rest >> 2;
            int co = half * 16 + (lane & 15), ci = chunk * 32 + (lane >> 4) * 8 + j;
            ws[W1P_OFF + idx] = f2bf(w1[(co * 64 + ci) * 81 + tap]);
        } else if (idx < 165888 + 82944) {
            int i2 = idx - 165888;
            int j = i2 & 7, lane = (i2 >> 3) & 63, rest = i2 >> 9;
            int half = rest & 1, tap = rest >> 1;
            int co = half * 16 + (lane & 15), ci = (lane >> 4) * 8 + j;
            ws[W2P_OFF + i2] = f2bf(w2[(co * 32 + ci) * 81 + tap]);
        } else if (idx < 165888 + 82944 + 2048) {
            int i3 = idx - (165888 + 82944);
            int j = i3 & 7, lane = (i3 >> 3) & 63, rest = i3 >> 9;   // chunk*2+half
            int half = rest & 1, chunk = rest >> 1;
            int co = half * 16 + (lane & 15), ci = chunk * 32 + (lane >> 4) * 8 + j;
            ws[W3P_OFF + i3] = f2bf(w3[co * 64 + ci]);
        } else if (idx < 250880 + 32768) {
            int i4 = idx - 250880;                        // [tap][chunk][half][lane][8]
            int j = i4 & 7, lane = (i4 >> 3) & 63, rest = i4 >> 9;
            int half = rest & 1, chunk = (rest >> 1) & 1, tap = rest >> 2;
            int co = half * 16 + (lane & 15), ci = chunk * 32 + (lane >> 4) * 8 + j;
            ws[UPWP_OFF + i4] = f2bf(upw[(ci * 32 + co) * 16 + tap]);   // [Cin][Cout][taps]
        }
    }

    // ---- xc_copy: x2 -> xcb channels 0..31 via padded-LDS transpose ----
    int b = bid >> 8;
    int pos_base = (bid & 255) * 256;
    u16* xcb = ws + XCB_OFF;
    #pragma unroll
    for (int c = 0; c < 32; ++c) {
        lds[tid * 40 + c] = f2bf(x2[((b * 32 + c) << 16) + pos_base + tid]);
    }
    __syncthreads();
    #pragma unroll
    for (int k = 0; k < 4; ++k) {
        int f = k * 256 + tid;
        int u = f & 3, pos = f >> 2;
        uint4 v = *(const uint4*)(lds + pos * 40 + u * 8);
        *(uint4*)(xcb + (size_t)((b << 16) + pos_base + pos) * 64 + u * 8) = v;
    }
}

// ---------------------------------------------------------------------------
// xc_up (r14 form): grid 512 = [b2][j64][tp4]; one tap/wave.
// ---------------------------------------------------------------------------
__global__ __launch_bounds__(256) void xc_up_mfma(const float* __restrict__ x1,
                                                  const u16* __restrict__ upwp,
                                                  const float* __restrict__ up_b,
                                                  u16* __restrict__ xcb) {
    __shared__ u16 lds[64 * 72];                 // 9 KB tile, pad 72
    int tid = threadIdx.x;
    int wv = tid >> 6, lane = tid & 63;
    int q = lane >> 4, m = lane & 15;
    int bid = blockIdx.x;                        // [b2][j64][tp4]
    int tp = bid & 3, j = (bid >> 2) & 63, b = bid >> 8;
    int pos_base = j * 64;

    // Phase A: transpose 64 pos x 64 ch into LDS channels-last
    #pragma unroll
    for (int g = 0; g < 16; ++g) {
        int c = g * 4 + wv;                      // wave-uniform channel
        lds[lane * 72 + c] = f2bf(x1[((b * 64 + c) << 12) + pos_base + lane]);
    }
    __syncthreads();

    // Phase B: ONE tap per wave
    const short8* wv8 = (const short8*)upwp;
    float4 bi0 = ((const float4*)up_b)[q];       // co = q*4+r
    float4 bi1 = ((const float4*)up_b)[4 + q];   // co = 16+q*4+r
    int it = j >> 3, id = j & 7;

    int tap = tp * 4 + wv;
    f32x4 acc[4][2];
    #pragma unroll
    for (int g = 0; g < 4; ++g) {
        acc[g][0] = (f32x4){bi0.x, bi0.y, bi0.z, bi0.w};
        acc[g][1] = (f32x4){bi1.x, bi1.y, bi1.z, bi1.w};
    }
    #pragma unroll
    for (int chunk = 0; chunk < 2; ++chunk) {
        short8 a0 = wv8[((tap * 2 + chunk) * 2 + 0) * 64 + lane];
        short8 a1 = wv8[((tap * 2 + chunk) * 2 + 1) * 64 + lane];
        #pragma unroll
        for (int g = 0; g < 4; ++g) {
            short8 bf = *(const short8*)(lds + (g * 16 + m) * 72 + chunk * 32 + q * 8);
            acc[g][0] = MFMA(a0, bf, acc[g][0]);
            acc[g][1] = MFMA(a1, bf, acc[g][1]);
        }
    }
    // epilogue: C/D col = ipos-local (lane&15), row = co-in-half = q*4+r.
    int pt = tap >> 3, pd = (tap >> 2) & 1, ph = (tap >> 1) & 1, pw = tap & 1;
    int oT = 2 * it + pt, oD = 2 * id + pd, oW = 2 * (m & 7) + pw;
    #pragma unroll
    for (int g = 0; g < 4; ++g) {
        int ih = g * 2 + (m >> 3);
        int opos = oT * 4096 + oD * 256 + (2 * ih + ph) * 16 + oW;
        u16* op = xcb + (size_t)((b << 16) + opos) * 64 + 32 + q * 4;
        #pragma unroll
        for (int half = 0; half < 2; ++half) {
            f32x4 v = acc[g][half];
            uint2 o;
            o.x = (unsigned)f2bf(v.x) | ((unsigned)f2bf(v.y) << 16);
            o.y = (unsigned)f2bf(v.z) | ((unsigned)f2bf(v.w) << 16);
            *(uint2*)(op + half * 16) = o;
        }
    }
}

// ---------------------------------------------------------------------------
// conv1: exact r12 best structure (dbuf 54 KB, 2 blk/CU, wave = ci-chunk x
// co-half, weight-first vmcnt order, gload staging, XCD pinning). Untouched.
// ---------------------------------------------------------------------------
__global__ __launch_bounds__(256, 2) void conv1_mfma(const u16* __restrict__ xcb,
                                                     const u16* __restrict__ w1p,
                                                     const float* __restrict__ b1,
                                                     const u16* __restrict__ zpad,
                                                     u16* __restrict__ y1b) {
    __shared__ __attribute__((aligned(16))) u16 lds[27648];   // 54 KB (pad: force 2 blk/CU)
    int tid = threadIdx.x;
    int lane = tid & 63, wv = tid >> 6;
    int q = lane >> 4, m = lane & 15;
    int c = wv & 1, hf = wv >> 1;                // ci-chunk, co-half
    int bid = blockIdx.x;
    int xcd = bid & 7;                           // xcd = b*4 + tq (L2 pinning)
    int b = xcd >> 2, tq = xcd & 3;
    int loc = bid >> 3;                          // 128 blocks per xcd
    int hB = loc & 1;
    int d = (loc >> 1) & 15;
    int tl = (loc >> 5) & 3;
    int t = tq * 4 + tl;
    int h0 = hB * 8;
    int rot = (bid * 5) % 9;                     // plane rotation (5 coprime 9)

    int gofs[6], lofs[6];
    bool st[6], inr[6];
    #pragma unroll
    for (int k = 0; k < 6; ++k) {
        int ui = tid + k * 256;
        int hh = ui / 144, rem = ui - hh * 144;
        int p = rem >> 3, w = rem & 7;
        int u_src = w ^ (p & 7);                 // inverse of the read-side XOR
        int gh = h0 - 1 + hh, gw = p - 1;
        st[k] = ui < 1440;
        inr[k] = st[k] && ((unsigned)gh < 16u) && ((unsigned)gw < 16u);
        gofs[k] = (gh * 16 + gw) * 64 + u_src * 8;
        lofs[k] = ui * 8;                        // u16 units; byte = ui*16
    }

    f32x4 acc[8];                                // [row i], this wave's co-half
    if (c == 0) {
        float4 bi = ((const float4*)b1)[hf * 4 + q];
        #pragma unroll
        for (int i = 0; i < 8; ++i)
            acc[i] = (f32x4){bi.x, bi.y, bi.z, bi.w};
    } else {
        #pragma unroll
        for (int i = 0; i < 8; ++i)
            acc[i] = (f32x4){0.f, 0.f, 0.f, 0.f};
    }
    const short8* w1v = (const short8*)w1p;

    auto issue_plane = [&](int ktd, int bb) {
        int kt = ktd / 3, kd = ktd - kt * 3;
        int tt = t + kt - 1, dd = d + kd - 1;
        bool pv = ((unsigned)tt < 16u) && ((unsigned)dd < 16u);
        const u16* src = xcb + (size_t)(((b * 16 + tt) * 16 + dd)) * 16384;
        #pragma unroll
        for (int k = 0; k < 6; ++k) {
            if (st[k]) {
                const u16* g = (pv && inr[k]) ? (src + gofs[k]) : zpad;
                gload16(g, lds + bb * 13824 + lofs[k]);
            }
        }
    };

    issue_plane(rot, 0);
    for (int s = 0; s < 9; ++s) {
        int ktd = rot + s; if (ktd >= 9) ktd -= 9;
        int kt = ktd / 3, kd = ktd - kt * 3;
        __syncthreads();                          // buf[s&1] ready (drains vmcnt)
        // ---- 1. weight loads FIRST (oldest vmcnt ops of this phase) ----
        short8 W[3][3];                           // [kw][kh], this wave's (c, hf)
        #pragma unroll
        for (int kw = 0; kw < 3; ++kw)
            #pragma unroll
            for (int kh = 0; kh < 3; ++kh) {
                int tap = ((kt * 3 + kd) * 3 + kh) * 3 + kw;
                W[kw][kh] = w1v[((tap * 2 + c) * 2 + hf) * 64 + lane];
            }
        __builtin_amdgcn_sched_barrier(0);        // pin: weights emitted before prefetch
        // ---- 2. prefetch next plane (newer vmcnt ops -> never force-drained)
        if (s < 8) {
            int nk = ktd + 1; if (nk >= 9) nk -= 9;
            issue_plane(nk, (s + 1) & 1);
        }
        __builtin_amdgcn_sched_barrier(0);
        // ---- 3. MFMA phase: all 8 rows, one co-half ----
        const u16* L = lds + (s & 1) * 13824;
        __builtin_amdgcn_s_setprio(1);
        #pragma unroll
        for (int kw = 0; kw < 3; ++kw) {
            int p = kw + m, pm = p & 7;
            int bo = p * 64 + ((((c << 2) | q) ^ pm) << 3);
            short8 R[10];
            #pragma unroll
            for (int r = 0; r < 10; ++r)          // halo rows 0..9
                R[r] = *(const short8*)(L + r * 1152 + bo);
            #pragma unroll
            for (int kh = 0; kh < 3; ++kh) {
                #pragma unroll
                for (int i = 0; i < 8; ++i)
                    acc[i] = MFMA(W[kw][kh], R[i + kh], acc[i]);
            }
        }
        __builtin_amdgcn_s_setprio(0);
    }

    // ---- K-reduction: chunk1 partials -> chunk0, via LDS overlay (16 KB) ----
    __syncthreads();
    f32x4* buf = (f32x4*)lds;
    if (c == 1) {
        #pragma unroll
        for (int i = 0; i < 8; ++i)
            buf[(hf * 8 + i) * 64 + lane] = acc[i];
    }
    __syncthreads();
    if (c == 0) {
        int obase = ((b * 16 + t) * 16 + d) * 256 + h0 * 16 + m;
        #pragma unroll
        for (int i = 0; i < 8; ++i) {
            int pos = obase + i * 16;
            f32x4 v = acc[i];
            f32x4 w = buf[(hf * 8 + i) * 64 + lane];
            v.x += w.x; v.y += w.y; v.z += w.z; v.w += w.w;
            unsigned r0 = f2bf(fmaxf(v.x, 0.f)), r1 = f2bf(fmaxf(v.y, 0.f));
            unsigned r2 = f2bf(fmaxf(v.z, 0.f)), r3 = f2bf(fmaxf(v.w, 0.f));
            uint2 o;
            o.x = r0 | (r1 << 16);
            o.y = r2 | (r3 << 16);
            *(uint2*)(y1b + (size_t)pos * 32 + hf * 16 + q * 4) = o;
        }
    }
}

// ---------------------------------------------------------------------------
// conv2 r16: BARRIER-FREE DIRECT-FROM-L2. No LDS, no staging, zero main-loop
// barriers — waves free-run, so the phase serialization that pins conv1 at
// 2.2x floor (stage->drain->LDS burst->MFMA burst, serial per r11-r13 pairs)
// cannot occur. Pixel B-fragments are per-lane 16B global loads (wave covers
// a contiguous ~1KB row-span, coalesced; OOB lanes -> zpad), y1b slice is
// L2-hot via XCD pinning (the fused 1x1 skip already runs this pattern).
// 4 waves = 4 rowgroups x 4 rows, both co-halves, full K per wave (no
// K-reduction). No LDS -> __launch_bounds__(256,4), 16 waves/CU.
// ---------------------------------------------------------------------------
__global__ __launch_bounds__(256, 4) void conv2_mfma(const u16* __restrict__ y1b,
                                                     const u16* __restrict__ xcb,
                                                     const u16* __restrict__ w2p,
                                                     const u16* __restrict__ w3p,
                                                     const float* __restrict__ b2,
                                                     const float* __restrict__ b3,
                                                     const u16* __restrict__ zpad,
                                                     float* __restrict__ out) {
    int tid = threadIdx.x;
    int lane = tid & 63, rg = tid >> 6;          // rowgroup 0..3 (4 rows each)
    int q = lane >> 4, m = lane & 15;
    int bid = blockIdx.x;
    // grid 512: xcd = bid&7 = b*4 + t_quad (L2 capacity pinning)
    int xcd = bid & 7;
    int b = xcd >> 2, tq = xcd & 3;
    int loc = bid >> 3;                          // 64 blocks per xcd
    int d = loc & 15;
    int tl = (loc >> 4) & 3;
    int t = tq * 4 + tl;

    // per-kw column offset/validity (lane-constant across planes)
    int colofs[3]; bool colok[3];
    #pragma unroll
    for (int kw = 0; kw < 3; ++kw) {
        int gw = kw + m - 1;
        colok[kw] = (unsigned)gw < 16u;
        colofs[kw] = gw * 32 + q * 8;            // u16 units within plane
    }

    f32x4 acc[4][2];                             // [row i][co half]
    #pragma unroll
    for (int hf = 0; hf < 2; ++hf) {
        float4 p0 = ((const float4*)b2)[hf * 4 + q];
        float4 s0 = ((const float4*)b3)[hf * 4 + q];
        #pragma unroll
        for (int i = 0; i < 4; ++i)
            acc[i][hf] = (f32x4){p0.x + s0.x, p0.y + s0.y, p0.z + s0.z, p0.w + s0.w};
    }
    const short8* w2v = (const short8*)w2p;

    #pragma unroll
    for (int ktd = 0; ktd < 9; ++ktd) {
        int kt = ktd / 3, kd = ktd - kt * 3;
        int tt = t + kt - 1, dd = d + kd - 1;
        bool pv = ((unsigned)tt < 16u) && ((unsigned)dd < 16u);
        const u16* src = y1b + (size_t)(((b * 16 + tt) * 16 + dd)) * 8192;
        #pragma unroll
        for (int kw = 0; kw < 3; ++kw) {
            short8 R[6];
            #pragma unroll
            for (int r = 0; r < 6; ++r) {         // input rows rg*4-1 .. rg*4+4
                int gh = rg * 4 + r - 1;          // wave-uniform
                bool ok = pv && colok[kw] && ((unsigned)gh < 16u);
                const u16* g = ok ? (src + gh * 512 + colofs[kw]) : zpad;
                R[r] = *(const short8*)g;
            }
            #pragma unroll
            for (int kh = 0; kh < 3; ++kh) {
                int tap = (ktd * 3 + kh) * 3 + kw;
                short8 a0 = w2v[(tap * 2 + 0) * 64 + lane];
                short8 a1 = w2v[(tap * 2 + 1) * 64 + lane];
                #pragma unroll
                for (int i = 0; i < 4; ++i) {
                    acc[i][0] = MFMA(a0, R[i + kh], acc[i][0]);
                    acc[i][1] = MFMA(a1, R[i + kh], acc[i][1]);
                }
            }
        }
    }

    // ---- fused 1x1 skip conv from xc (Cin=64, 2 chunks), B direct from global
    const short8* w3v = (const short8*)w3p;
    int lpos0 = (t * 16 + d) * 256 + (rg * 4) * 16 + m;        // batch-local pos
    int gpos0 = (b << 16) + lpos0;                             // global pos (ws arrays)
    #pragma unroll
    for (int chunk = 0; chunk < 2; ++chunk) {
        short8 a0 = w3v[(chunk * 2 + 0) * 64 + lane];
        short8 a1 = w3v[(chunk * 2 + 1) * 64 + lane];
        #pragma unroll
        for (int i = 0; i < 4; ++i) {
            short8 bf = *(const short8*)(xcb + (size_t)(gpos0 + i * 16) * 64 + ((chunk << 2) | q) * 8);
            acc[i][0] = MFMA(a0, bf, acc[i][0]);
            acc[i][1] = MFMA(a1, bf, acc[i][1]);
        }
    }

    // ---- epilogue: ReLU, fp32 store to [b][co][local_pos] ----
    #pragma unroll
    for (int i = 0; i < 4; ++i) {
        int lpos = lpos0 + i * 16;
        #pragma unroll
        for (int hf = 0; hf < 2; ++hf) {
            f32x4 v = acc[i][hf];
            int co = hf * 16 + q * 4;
            float* op = out + (((size_t)(b * 32 + co)) << 16) + lpos;
            op[0ull << 16] = fmaxf(v.x, 0.f);
            op[1ull << 16] = fmaxf(v.y, 0.f);
            op[2ull << 16] = fmaxf(v.z, 0.f);
            op[3ull << 16] = fmaxf(v.w, 0.f);
        }
    }
}

extern "C" void kernel_launch(void* const* d_in, const int* in_sizes, int n_in,
                              void* d_out, int out_size, void* d_ws, size_t ws_size,
                              hipStream_t stream) {
    const float* x1   = (const float*)d_in[0];
    const float* x2   = (const float*)d_in[1];
    const float* up_w = (const float*)d_in[2];
    const float* up_b = (const float*)d_in[3];
    const float* w1   = (const float*)d_in[4];
    const float* b1   = (const float*)d_in[5];
    const float* w2   = (const float*)d_in[6];
    const float* b2   = (const float*)d_in[7];
    const float* w3   = (const float*)d_in[8];
    const float* b3   = (const float*)d_in[9];
    u16* ws  = (u16*)d_ws;
    float* out = (float*)d_out;

    setup<<<512, 256, 0, stream>>>(w1, w2, w3, up_w, x2, ws);
    xc_up_mfma<<<512, 256, 0, stream>>>(x1, ws + UPWP_OFF, up_b, ws + XCB_OFF);
    conv1_mfma<<<1024, 256, 0, stream>>>(ws + XCB_OFF, ws + W1P_OFF, b1,
                                         ws + ZPAD_OFF, ws + Y1B_OFF);
    conv2_mfma<<<512, 256, 0, stream>>>(ws + Y1B_OFF, ws + XCB_OFF, ws + W2P_OFF,
                                        ws + W3P_OFF, b2, b3, ws + ZPAD_OFF, out);
}

// Round 17
// 155.000 us; speedup vs baseline: 1.0982x; 1.0982x over previous
//
#include <hip/hip_runtime.h>

typedef unsigned short u16;
typedef __attribute__((ext_vector_type(8))) short short8;   // 8 bf16 (guide-verified MFMA frag type)
typedef __attribute__((ext_vector_type(4))) float f32x4;

// Workspace layout (u16 element offsets).
#define XCB_OFF  0          // xc  channels-last bf16 [2][16^4][64] = 8,388,608
#define Y1B_OFF  8388608    // Y1  channels-last bf16 [2][16^4][32] = 4,194,304
#define W1P_OFF  12582912   // w1 prepacked [tap81][chunk2][half2][lane64][8] = 165,888
#define W2P_OFF  12748800   // w2 prepacked [tap81][half2][lane64][8]         =  82,944
#define W3P_OFF  12831744   // w3 prepacked [chunk2][half2][lane64][8]        =   2,048
#define UPWP_OFF 12833792   // up_w prepacked [tap16][chunk2][half2][lane64][8] = 32,768
#define ZPAD_OFF 12866560   // 64 u16 of zeros — OOB redirect target for global_load_lds

__device__ __forceinline__ u16 f2bf(float v) {   // RNE fp32 -> bf16 bits
    unsigned u = __builtin_bit_cast(unsigned, v);
    u += 0x7FFFu + ((u >> 16) & 1u);
    return (u16)(u >> 16);
}

__device__ __forceinline__ f32x4 MFMA(short8 a, short8 b, f32x4 c) {
    return __builtin_amdgcn_mfma_f32_16x16x32_bf16(a, b, c, 0, 0, 0);
}

// async global->LDS, 16B per lane. LDS dest must be linear (wave base + lane*16);
// global source is per-lane (pre-swizzled / OOB-redirected).
typedef const __attribute__((address_space(1))) u16 gas_u16;
typedef __attribute__((address_space(3))) u16 las_u16;
__device__ __forceinline__ void gload16(const u16* g, u16* l) {
    __builtin_amdgcn_global_load_lds((gas_u16*)g, (las_u16*)l, 16, 0, 0);
}

// ---------------------------------------------------------------------------
// setup: fused (xc_copy | prepack weights) + ZPAD zeroing. [r12 form]
// ---------------------------------------------------------------------------
__global__ __launch_bounds__(256) void setup(const float* __restrict__ w1,
                                             const float* __restrict__ w2,
                                             const float* __restrict__ w3,
                                             const float* __restrict__ upw,
                                             const float* __restrict__ x2,
                                             u16* __restrict__ ws) {
    __shared__ u16 lds[256 * 40];
    int bid = blockIdx.x;
    int tid = threadIdx.x;
    if (bid == 0 && tid < 64) ws[ZPAD_OFF + tid] = 0;   // zero redirect target
    if (bid < 512) {
        // ---- xc_copy: x2 -> xcb channels 0..31 via padded-LDS transpose
        int b = bid >> 8;
        int pos_base = (bid & 255) * 256;
        u16* xcb = ws + XCB_OFF;
        #pragma unroll
        for (int c = 0; c < 32; ++c) {
            lds[tid * 40 + c] = f2bf(x2[((b * 32 + c) << 16) + pos_base + tid]);
        }
        __syncthreads();
        #pragma unroll
        for (int k = 0; k < 4; ++k) {
            int f = k * 256 + tid;
            int u = f & 3, pos = f >> 2;
            uint4 v = *(const uint4*)(lds + pos * 40 + u * 8);
            *(uint4*)(xcb + (size_t)((b << 16) + pos_base + pos) * 64 + u * 8) = v;
        }
    } else {
        // ---- prepack into MFMA A-frag order: a[lane][j] = A[m=lane&15][k=(lane>>4)*8+j]
        int idx = (bid - 512) * 256 + tid;
        if (idx < 165888) {
            int j = idx & 7, lane = (idx >> 3) & 63, rest = idx >> 9;
            int half = rest & 1, chunk = (rest >> 1) & 1, tap = rest >> 2;
            int co = half * 16 + (lane & 15), ci = chunk * 32 + (lane >> 4) * 8 + j;
            ws[W1P_OFF + idx] = f2bf(w1[(co * 64 + ci) * 81 + tap]);
        } else if (idx < 165888 + 82944) {
            int i2 = idx - 165888;
            int j = i2 & 7, lane = (i2 >> 3) & 63, rest = i2 >> 9;
            int half = rest & 1, tap = rest >> 1;
            int co = half * 16 + (lane & 15), ci = (lane >> 4) * 8 + j;
            ws[W2P_OFF + i2] = f2bf(w2[(co * 32 + ci) * 81 + tap]);
        } else if (idx < 165888 + 82944 + 2048) {
            int i3 = idx - (165888 + 82944);
            int j = i3 & 7, lane = (i3 >> 3) & 63, rest = i3 >> 9;   // chunk*2+half
            int half = rest & 1, chunk = rest >> 1;
            int co = half * 16 + (lane & 15), ci = chunk * 32 + (lane >> 4) * 8 + j;
            ws[W3P_OFF + i3] = f2bf(w3[co * 64 + ci]);
        } else if (idx < 250880 + 32768) {
            int i4 = idx - 250880;                        // [tap][chunk][half][lane][8]
            int j = i4 & 7, lane = (i4 >> 3) & 63, rest = i4 >> 9;
            int half = rest & 1, chunk = (rest >> 1) & 1, tap = rest >> 2;
            int co = half * 16 + (lane & 15), ci = chunk * 32 + (lane >> 4) * 8 + j;
            ws[UPWP_OFF + i4] = f2bf(upw[(ci * 32 + co) * 16 + tap]);   // [Cin][Cout][taps]
        }
    }
}

// ---------------------------------------------------------------------------
// xc_up: tconv4d(k2,s2) fused with x1 transpose. grid 256 = [b2][j64][tp2].
// [r12 form]
// ---------------------------------------------------------------------------
__global__ __launch_bounds__(256) void xc_up_mfma(const float* __restrict__ x1,
                                                  const u16* __restrict__ upwp,
                                                  const float* __restrict__ up_b,
                                                  u16* __restrict__ xcb) {
    __shared__ u16 lds[64 * 72];                 // 9 KB tile, pad 72
    int tid = threadIdx.x;
    int wv = tid >> 6, lane = tid & 63;
    int q = lane >> 4, m = lane & 15;
    int bid = blockIdx.x;                        // [b2][j64][tp2]
    int tp = bid & 1, j = (bid >> 1) & 63, b = bid >> 7;
    int pos_base = j * 64;

    // Phase A: transpose 64 pos x 64 ch into LDS channels-last
    #pragma unroll
    for (int g = 0; g < 16; ++g) {
        int c = g * 4 + wv;                      // wave-uniform channel
        lds[lane * 72 + c] = f2bf(x1[((b * 64 + c) << 12) + pos_base + lane]);
    }
    __syncthreads();

    // Phase B: 2 taps per wave
    const short8* wv8 = (const short8*)upwp;
    float4 bi0 = ((const float4*)up_b)[q];       // co = q*4+r
    float4 bi1 = ((const float4*)up_b)[4 + q];   // co = 16+q*4+r
    int it = j >> 3, id = j & 7;

    for (int tt = 0; tt < 2; ++tt) {
        int tap = tp * 8 + wv * 2 + tt;
        f32x4 acc[4][2];
        #pragma unroll
        for (int g = 0; g < 4; ++g) {
            acc[g][0] = (f32x4){bi0.x, bi0.y, bi0.z, bi0.w};
            acc[g][1] = (f32x4){bi1.x, bi1.y, bi1.z, bi1.w};
        }
        #pragma unroll
        for (int chunk = 0; chunk < 2; ++chunk) {
            short8 a0 = wv8[((tap * 2 + chunk) * 2 + 0) * 64 + lane];
            short8 a1 = wv8[((tap * 2 + chunk) * 2 + 1) * 64 + lane];
            #pragma unroll
            for (int g = 0; g < 4; ++g) {
                short8 bf = *(const short8*)(lds + (g * 16 + m) * 72 + chunk * 32 + q * 8);
                acc[g][0] = MFMA(a0, bf, acc[g][0]);
                acc[g][1] = MFMA(a1, bf, acc[g][1]);
            }
        }
        // epilogue: C/D col = ipos-local (lane&15), row = co-in-half = q*4+r.
        int pt = tap >> 3, pd = (tap >> 2) & 1, ph = (tap >> 1) & 1, pw = tap & 1;
        int oT = 2 * it + pt, oD = 2 * id + pd, oW = 2 * (m & 7) + pw;
        #pragma unroll
        for (int g = 0; g < 4; ++g) {
            int ih = g * 2 + (m >> 3);
            int opos = oT * 4096 + oD * 256 + (2 * ih + ph) * 16 + oW;
            u16* op = xcb + (size_t)((b << 16) + opos) * 64 + 32 + q * 4;
            #pragma unroll
            for (int half = 0; half < 2; ++half) {
                f32x4 v = acc[g][half];
                uint2 o;
                o.x = (unsigned)f2bf(v.x) | ((unsigned)f2bf(v.y) << 16);
                o.y = (unsigned)f2bf(v.z) | ((unsigned)f2bf(v.w) << 16);
                *(uint2*)(op + half * 16) = o;
            }
        }
    }
}

// ---------------------------------------------------------------------------
// conv1: 3^4 conv Cin=64->Cout=32 +bias+ReLU -> Y1. [r12 best — verified
// 155.63 us total] Wave = (ci-chunk c) x (co-half hf), all 8 rows; weight
// loads halved vs rowgroup split. Weight-first vmcnt order + sched_barrier
// pins (r11's validated +7us mechanism: in-order vmcnt retirement means
// weights issued BEFORE the prefetch keep the prefetch in flight under the
// MFMA cluster). gload dbuf 54 KB (pad forces exactly 2 blk/CU), XCD
// pinning xcd = b*4+tq, plane rotation, setprio.
// ---------------------------------------------------------------------------
__global__ __launch_bounds__(256, 2) void conv1_mfma(const u16* __restrict__ xcb,
                                                     const u16* __restrict__ w1p,
                                                     const float* __restrict__ b1,
                                                     const u16* __restrict__ zpad,
                                                     u16* __restrict__ y1b) {
    __shared__ __attribute__((aligned(16))) u16 lds[27648];   // 54 KB (pad: force 2 blk/CU)
    int tid = threadIdx.x;
    int lane = tid & 63, wv = tid >> 6;
    int q = lane >> 4, m = lane & 15;
    int c = wv & 1, hf = wv >> 1;                // ci-chunk, co-half
    int bid = blockIdx.x;
    int xcd = bid & 7;                           // xcd = b*4 + tq (L2 pinning)
    int b = xcd >> 2, tq = xcd & 3;
    int loc = bid >> 3;                          // 128 blocks per xcd
    int hB = loc & 1;
    int d = (loc >> 1) & 15;
    int tl = (loc >> 5) & 3;
    int t = tq * 4 + tl;
    int h0 = hB * 8;
    int rot = (bid * 5) % 9;                     // plane rotation (5 coprime 9)

    // staging: slot ui = tid + k*256 (linear LDS, 16B each). Source swizzled.
    int gofs[6], lofs[6];
    bool st[6], inr[6];
    #pragma unroll
    for (int k = 0; k < 6; ++k) {
        int ui = tid + k * 256;
        int hh = ui / 144, rem = ui - hh * 144;
        int p = rem >> 3, w = rem & 7;
        int u_src = w ^ (p & 7);                 // inverse of the read-side XOR
        int gh = h0 - 1 + hh, gw = p - 1;
        st[k] = ui < 1440;
        inr[k] = st[k] && ((unsigned)gh < 16u) && ((unsigned)gw < 16u);
        gofs[k] = (gh * 16 + gw) * 64 + u_src * 8;
        lofs[k] = ui * 8;                        // u16 units; byte = ui*16
    }

    f32x4 acc[8];                                // [row i], this wave's co-half
    if (c == 0) {
        float4 bi = ((const float4*)b1)[hf * 4 + q];
        #pragma unroll
        for (int i = 0; i < 8; ++i)
            acc[i] = (f32x4){bi.x, bi.y, bi.z, bi.w};
    } else {
        #pragma unroll
        for (int i = 0; i < 8; ++i)
            acc[i] = (f32x4){0.f, 0.f, 0.f, 0.f};
    }
    const short8* w1v = (const short8*)w1p;

    auto issue_plane = [&](int ktd, int bb) {
        int kt = ktd / 3, kd = ktd - kt * 3;
        int tt = t + kt - 1, dd = d + kd - 1;
        bool pv = ((unsigned)tt < 16u) && ((unsigned)dd < 16u);
        const u16* src = xcb + (size_t)(((b * 16 + tt) * 16 + dd)) * 16384;
        #pragma unroll
        for (int k = 0; k < 6; ++k) {
            if (st[k]) {
                const u16* g = (pv && inr[k]) ? (src + gofs[k]) : zpad;
                gload16(g, lds + bb * 13824 + lofs[k]);
            }
        }
    };

    issue_plane(rot, 0);
    for (int s = 0; s < 9; ++s) {
        int ktd = rot + s; if (ktd >= 9) ktd -= 9;
        int kt = ktd / 3, kd = ktd - kt * 3;
        __syncthreads();                          // buf[s&1] ready (drains vmcnt)
        // ---- 1. weight loads FIRST (oldest vmcnt ops of this phase) ----
        short8 W[3][3];                           // [kw][kh], this wave's (c, hf)
        #pragma unroll
        for (int kw = 0; kw < 3; ++kw)
            #pragma unroll
            for (int kh = 0; kh < 3; ++kh) {
                int tap = ((kt * 3 + kd) * 3 + kh) * 3 + kw;
                W[kw][kh] = w1v[((tap * 2 + c) * 2 + hf) * 64 + lane];
            }
        __builtin_amdgcn_sched_barrier(0);        // pin: weights emitted before prefetch
        // ---- 2. prefetch next plane (newer vmcnt ops -> never force-drained)
        if (s < 8) {
            int nk = ktd + 1; if (nk >= 9) nk -= 9;
            issue_plane(nk, (s + 1) & 1);
        }
        __builtin_amdgcn_sched_barrier(0);
        // ---- 3. MFMA phase: all 8 rows, one co-half ----
        const u16* L = lds + (s & 1) * 13824;
        __builtin_amdgcn_s_setprio(1);
        #pragma unroll
        for (int kw = 0; kw < 3; ++kw) {
            int p = kw + m, pm = p & 7;
            int bo = p * 64 + ((((c << 2) | q) ^ pm) << 3);
            short8 R[10];
            #pragma unroll
            for (int r = 0; r < 10; ++r)          // halo rows 0..9
                R[r] = *(const short8*)(L + r * 1152 + bo);
            #pragma unroll
            for (int kh = 0; kh < 3; ++kh) {
                #pragma unroll
                for (int i = 0; i < 8; ++i)
                    acc[i] = MFMA(W[kw][kh], R[i + kh], acc[i]);
            }
        }
        __builtin_amdgcn_s_setprio(0);
    }

    // ---- K-reduction: chunk1 partials -> chunk0, via LDS overlay (16 KB) ----
    __syncthreads();
    f32x4* buf = (f32x4*)lds;
    if (c == 1) {
        #pragma unroll
        for (int i = 0; i < 8; ++i)
            buf[(hf * 8 + i) * 64 + lane] = acc[i];
    }
    __syncthreads();
    if (c == 0) {
        int obase = ((b * 16 + t) * 16 + d) * 256 + h0 * 16 + m;
        #pragma unroll
        for (int i = 0; i < 8; ++i) {
            int pos = obase + i * 16;
            f32x4 v = acc[i];
            f32x4 w = buf[(hf * 8 + i) * 64 + lane];
            v.x += w.x; v.y += w.y; v.z += w.z; v.w += w.w;
            unsigned r0 = f2bf(fmaxf(v.x, 0.f)), r1 = f2bf(fmaxf(v.y, 0.f));
            unsigned r2 = f2bf(fmaxf(v.z, 0.f)), r3 = f2bf(fmaxf(v.w, 0.f));
            uint2 o;
            o.x = r0 | (r1 << 16);
            o.y = r2 | (r3 << 16);
            *(uint2*)(y1b + (size_t)pos * 32 + hf * 16 + q * 4) = o;
        }
    }
}

// ---------------------------------------------------------------------------
// conv2: 3^4 conv Cin=32->Cout=32 + fused 1x1 skip + biases + ReLU -> fp32.
// [r12 best] Wave = (co-half hf) x (row-half rh, 8 rows); staged gload dbuf;
// weight-first order; XCD pinning; rotation; setprio. (r15 LDS epilogue and
// r16 barrier-free direct-L2 variants both REGRESSED — staging is
// load-bearing here.)
// ---------------------------------------------------------------------------
__global__ __launch_bounds__(256, 2) void conv2_mfma(const u16* __restrict__ y1b,
                                                     const u16* __restrict__ xcb,
                                                     const u16* __restrict__ w2p,
                                                     const u16* __restrict__ w3p,
                                                     const float* __restrict__ b2,
                                                     const float* __restrict__ b3,
                                                     const u16* __restrict__ zpad,
                                                     float* __restrict__ out) {
    __shared__ __attribute__((aligned(16))) u16 lds[20736];  // 2 x 1296 slots x 16B
    int tid = threadIdx.x;
    int lane = tid & 63, wv = tid >> 6;
    int q = lane >> 4, m = lane & 15;
    int hf = wv & 1, rh = wv >> 1;               // co-half, row-half
    int bid = blockIdx.x;
    // grid 512: xcd = bid&7 = b*4 + t_quad (L2 capacity pinning)
    int xcd = bid & 7;
    int b = xcd >> 2, tq = xcd & 3;
    int loc = bid >> 3;                          // 64 blocks per xcd
    int d = loc & 15;
    int tl = (loc >> 4) & 3;
    int t = tq * 4 + tl;
    int rot = (bid * 5) % 9;

    int gofs[6], lofs[6];
    bool st[6], inr[6];
    #pragma unroll
    for (int k = 0; k < 6; ++k) {
        int ui = tid + k * 256;
        int hh = ui / 72, rem = ui - hh * 72;
        int p = rem >> 2, w = rem & 3;
        int u_src = w ^ (p & 3);
        int gh = hh - 1, gw = p - 1;
        st[k] = ui < 1296;
        inr[k] = st[k] && ((unsigned)gh < 16u) && ((unsigned)gw < 16u);
        gofs[k] = (gh * 16 + gw) * 32 + u_src * 8;
        lofs[k] = ui * 8;
    }

    f32x4 acc[8];                                // [row i], this wave's co-half
    {
        float4 p0 = ((const float4*)b2)[hf * 4 + q];
        float4 s0 = ((const float4*)b3)[hf * 4 + q];
        #pragma unroll
        for (int i = 0; i < 8; ++i)
            acc[i] = (f32x4){p0.x + s0.x, p0.y + s0.y, p0.z + s0.z, p0.w + s0.w};
    }
    const short8* w2v = (const short8*)w2p;

    auto issue_plane = [&](int ktd, int bb) {
        int kt = ktd / 3, kd = ktd - kt * 3;
        int tt = t + kt - 1, dd = d + kd - 1;
        bool pv = ((unsigned)tt < 16u) && ((unsigned)dd < 16u);
        const u16* src = y1b + (size_t)(((b * 16 + tt) * 16 + dd)) * 8192;
        #pragma unroll
        for (int k = 0; k < 6; ++k) {
            if (st[k]) {
                const u16* g = (pv && inr[k]) ? (src + gofs[k]) : zpad;
                gload16(g, lds + bb * 10368 + lofs[k]);
            }
        }
    };

    issue_plane(rot, 0);
    for (int s = 0; s < 9; ++s) {
        int ktd = rot + s; if (ktd >= 9) ktd -= 9;
        __syncthreads();                          // buf[s&1] ready
        // ---- 1. weight loads FIRST ----
        short8 W[3][3];                           // [kw][kh], this wave's hf
        #pragma unroll
        for (int kw = 0; kw < 3; ++kw)
            #pragma unroll
            for (int kh = 0; kh < 3; ++kh) {
                int tap = (ktd * 3 + kh) * 3 + kw;
                W[kw][kh] = w2v[(tap * 2 + hf) * 64 + lane];
            }
        __builtin_amdgcn_sched_barrier(0);
        // ---- 2. prefetch next plane ----
        if (s < 8) {
            int nk = ktd + 1; if (nk >= 9) nk -= 9;
            issue_plane(nk, (s + 1) & 1);
        }
        __builtin_amdgcn_sched_barrier(0);
        // ---- 3. MFMA phase: 8 rows, one co-half ----
        const u16* L = lds + (s & 1) * 10368;
        __builtin_amdgcn_s_setprio(1);
        #pragma unroll
        for (int kw = 0; kw < 3; ++kw) {
            int p = kw + m, pm = p & 3;
            int bo = p * 32 + ((q ^ pm) << 3);
            short8 R[10];
            #pragma unroll
            for (int r = 0; r < 10; ++r)          // halo rows rh*8 .. rh*8+9
                R[r] = *(const short8*)(L + (rh * 8 + r) * 576 + bo);
            #pragma unroll
            for (int kh = 0; kh < 3; ++kh) {
                #pragma unroll
                for (int i = 0; i < 8; ++i)
                    acc[i] = MFMA(W[kw][kh], R[i + kh], acc[i]);
            }
        }
        __builtin_amdgcn_s_setprio(0);
    }

    // ---- fused 1x1 skip conv from xc (Cin=64, 2 chunks), B direct from global
    const short8* w3v = (const short8*)w3p;
    int lpos0 = (t * 16 + d) * 256 + (rh * 8) * 16 + m;        // batch-local pos
    int gpos0 = (b << 16) + lpos0;                             // global pos (ws arrays)
    #pragma unroll
    for (int chunk = 0; chunk < 2; ++chunk) {
        short8 a = w3v[(chunk * 2 + hf) * 64 + lane];
        #pragma unroll
        for (int i = 0; i < 8; ++i) {
            short8 bf = *(const short8*)(xcb + (size_t)(gpos0 + i * 16) * 64 + ((chunk << 2) | q) * 8);
            acc[i] = MFMA(a, bf, acc[i]);
        }
    }

    // ---- epilogue: ReLU, fp32 store to [b][co][local_pos] ----
    #pragma unroll
    for (int i = 0; i < 8; ++i) {
        int lpos = lpos0 + i * 16;
        f32x4 v = acc[i];
        int co = hf * 16 + q * 4;
        float* op = out + (((size_t)(b * 32 + co)) << 16) + lpos;
        op[0ull << 16] = fmaxf(v.x, 0.f);
        op[1ull << 16] = fmaxf(v.y, 0.f);
        op[2ull << 16] = fmaxf(v.z, 0.f);
        op[3ull << 16] = fmaxf(v.w, 0.f);
    }
}

extern "C" void kernel_launch(void* const* d_in, const int* in_sizes, int n_in,
                              void* d_out, int out_size, void* d_ws, size_t ws_size,
                              hipStream_t stream) {
    const float* x1   = (const float*)d_in[0];
    const float* x2   = (const float*)d_in[1];
    const float* up_w = (const float*)d_in[2];
    const float* up_b = (const float*)d_in[3];
    const float* w1   = (const float*)d_in[4];
    const float* b1   = (const float*)d_in[5];
    const float* w2   = (const float*)d_in[6];
    const float* b2   = (const float*)d_in[7];
    const float* w3   = (const float*)d_in[8];
    const float* b3   = (const float*)d_in[9];
    u16* ws  = (u16*)d_ws;
    float* out = (float*)d_out;

    setup<<<1620, 256, 0, stream>>>(w1, w2, w3, up_w, x2, ws);
    xc_up_mfma<<<256, 256, 0, stream>>>(x1, ws + UPWP_OFF, up_b, ws + XCB_OFF);
    conv1_mfma<<<1024, 256, 0, stream>>>(ws + XCB_OFF, ws + W1P_OFF, b1,
                                         ws + ZPAD_OFF, ws + Y1B_OFF);
    conv2_mfma<<<512, 256, 0, stream>>>(ws + Y1B_OFF, ws + XCB_OFF, ws + W2P_OFF,
                                        ws + W3P_OFF, b2, b3, ws + ZPAD_OFF, out);
}